// Round 6
// baseline (37483.475 us; speedup 1.0000x reference)
//
#include <hip/hip_runtime.h>

typedef __attribute__((ext_vector_type(8))) short short8;
typedef __attribute__((ext_vector_type(4))) float f32x4;
typedef __attribute__((ext_vector_type(4))) unsigned short u16x4;
typedef __attribute__((ext_vector_type(4))) unsigned int u32x4;
typedef unsigned short ushort;
typedef unsigned int uint;
typedef unsigned long long ull;

#define MFMA16(a,b,c) __builtin_amdgcn_mfma_f32_16x16x32_bf16((a),(b),(c),0,0,0)

static __device__ __forceinline__ float bf2f(ushort u){
  union { uint i; float f; } z; z.i = ((uint)u) << 16; return z.f;
}
static __device__ __forceinline__ ushort f2bf(float f){
  union { float f; uint i; } z; z.f = f;
  uint x = z.i;
  uint r = (x + 0x7fffu + ((x >> 16) & 1u)) >> 16;   // RNE
  return (ushort)r;
}

// coherence-point (sc0 sc1 path) atomics: bypass stale L1/L2
static __device__ __forceinline__ ull ld_q64(const uint* p){
  return __hip_atomic_load((const ull*)p, __ATOMIC_RELAXED, __HIP_MEMORY_SCOPE_AGENT);
}
static __device__ __forceinline__ uint ld_q32(const uint* p){
  return __hip_atomic_load(p, __ATOMIC_RELAXED, __HIP_MEMORY_SCOPE_AGENT);
}
static __device__ __forceinline__ void st_q32(uint* p, uint v){
  asm volatile("global_store_dword %0, %1, off sc0 sc1" :: "v"(p), "v"(v) : "memory");
}
static __device__ __forceinline__ void st_q64(uint* p, ull v){
  asm volatile("global_store_dwordx2 %0, %1, off sc0 sc1" :: "v"(p), "v"(v) : "memory");
}
// pack two tagged u32s (value in high16) into one bf16x2
static __device__ __forceinline__ uint pk2(uint w1, uint w0){
  return __builtin_amdgcn_perm(w1, w0, 0x07060302u);   // {w0b2,w0b3,w1b2,w1b3}
}

// ---------------------------------------------------------------------------
// fp32 -> bf16 convert
// ---------------------------------------------------------------------------
__global__ __launch_bounds__(256) void cvt_k(
    const float* __restrict__ in, ushort* __restrict__ out, int n)
{
  int i = (blockIdx.x * 256 + threadIdx.x) * 4;
  if (i < n){
    float4 v = *(const float4*)(in + i);
    u16x4 o = { f2bf(v.x), f2bf(v.y), f2bf(v.z), f2bf(v.w) };
    *(u16x4*)(out + i) = o;
  }
}

// ---------------------------------------------------------------------------
// GEMM: C[M,N] = A[M,K](bf16) @ B[K,N](bf16) + bias[N](fp32).
// ---------------------------------------------------------------------------
template<int F32OUT>
__global__ __launch_bounds__(256) void gemm_bias_k(
    const ushort* __restrict__ A,
    const ushort* __restrict__ B,
    const float*  __restrict__ bias,
    void* __restrict__ Cv,
    int M, int N, int K)
{
  __shared__ __align__(16) ushort Blds[64 * 40];
  const int tid  = threadIdx.x;
  const int wid  = tid >> 6;
  const int lane = tid & 63;
  const int quad = lane >> 4;
  const int lc   = lane & 15;
  const int nb   = N >> 6;
  const int bn   = (blockIdx.x % nb) << 6;
  const int bm   = (blockIdx.x / nb) << 6;

  const int sk  = tid >> 3;
  const int scg = tid & 7;

  f32x4 acc[4] = {{0,0,0,0},{0,0,0,0},{0,0,0,0},{0,0,0,0}};
  const int arow = bm + wid * 16 + lc;
  const ushort* aptr = A + (size_t)arow * K + quad * 8;

  for (int k0 = 0; k0 < K; k0 += 32){
    short8 bv = *(const short8*)(B + (size_t)(k0 + sk) * N + bn + (scg << 3));
    #pragma unroll
    for (int i = 0; i < 8; ++i){
      int c = (scg << 3) + i;
      int p = c * 40 + (((sk >> 3) ^ (scg & 3)) << 3) + (sk & 7);
      Blds[p] = (ushort)bv[i];
    }
    __syncthreads();
    short8 av = *(const short8*)(aptr + k0);
    #pragma unroll
    for (int nt = 0; nt < 4; ++nt){
      int c2 = (nt << 4) + lc;
      int p  = c2 * 40 + ((quad ^ ((c2 >> 3) & 3)) << 3);
      short8 bfrag = *(const short8*)(Blds + p);
      acc[nt] = MFMA16(av, bfrag, acc[nt]);
    }
    __syncthreads();
  }
  #pragma unroll
  for (int nt = 0; nt < 4; ++nt){
    #pragma unroll
    for (int i = 0; i < 4; ++i){
      int m = bm + wid * 16 + quad * 4 + i;
      int n = bn + (nt << 4) + lc;
      float v = acc[nt][i] + bias[n];
      if (F32OUT) ((float*)Cv)[(size_t)m * N + n] = v;
      else        ((ushort*)Cv)[(size_t)m * N + n] = f2bf(v);
    }
  }
}

// ---------------------------------------------------------------------------
// Fused 3-layer pipelined GRU, TAGGED-EPOCH rings (no flags, no drains).
// 96 WGs x 384 thr. role=bid/32, g=bid%32 (units [16g,16g+16)).
// Ring element u32 = (bf16<<16)|tag, tag = t+1. Consumers retry the load+MFMA
// chain until all tags fresh (ballot). Producers fire sc0/sc1 stores only.
// Back-pressure (slot reuse, depth 8): tag-check h1/h2 rings at t-8.
// ---------------------------------------------------------------------------
#define NWG 96
#define RD 8

__global__ __launch_bounds__(384, 2) void rec3_k(
    const ushort* __restrict__ xw0,   // [32*1024,1536] bf16, row = b*1024+t
    const ushort* __restrict__ R0b,   // [512,1536]
    const ushort* __restrict__ Ksb,   // [512,1536]
    const ushort* __restrict__ Rsb,   // [512,1536]
    const float*  __restrict__ b0v,   // [2,1536]
    const float*  __restrict__ bsv,   // [2,1536]
    const float*  __restrict__ h00,
    const float*  __restrict__ h01,
    const float*  __restrict__ h02,
    const float*  __restrict__ av,    // [3]
    ushort* __restrict__ comb,        // [32*1024,512] bf16
    uint* __restrict__ rq)            // tagged rings, 1179648 u32
{
  __shared__ float m_lds[3][32][17];
  __shared__ float x_lds[3][32][17];
  __shared__ float bias_l[96];
  __shared__ __align__(16) ushort ks_lds[3 * 16 * 64 * 8];  // 48 KB

  const int tid  = threadIdx.x;
  const int wid  = tid >> 6;
  const int lane = tid & 63;
  const int quad = lane >> 4;
  const int lc   = lane & 15;
  const int bid  = blockIdx.x;
  const int role = bid >> 5;
  const int g    = bid & 31;
  const int ug0  = g << 4;
  const int gate = wid % 3, mtile = wid / 3;
  const int col0 = (gate << 9) + ug0;

  uint* hq  = rq + role * 131072;   // own h ring  [8][32][512]
  uint* hq1 = rq + 131072;
  uint* hq2 = rq + 262144;
  uint* oq  = rq + 393216;          // out0  [8][32][512]
  uint* pq  = rq + 524288;          // pred0 [8][32][512]
  uint* xq  = rq + 655360;          // xw1   [8][32][512][4]

  // ---- recurrent-weight fragments in VGPRs ----
  const ushort* Rw = (role == 0) ? R0b : Rsb;
  short8 bfragR[16];
  #pragma unroll
  for (int f = 0; f < 16; ++f){
    short8 v;
    #pragma unroll
    for (int j = 0; j < 8; ++j)
      v[j] = (short)Rw[(size_t)(f * 32 + quad * 8 + j) * 1536 + col0 + lc];
    bfragR[f] = v;
  }
  if (role > 0 && mtile == 0){
    #pragma unroll
    for (int f = 0; f < 16; ++f){
      short8 v;
      #pragma unroll
      for (int j = 0; j < 8; ++j)
        v[j] = (short)Ksb[(size_t)(f * 32 + quad * 8 + j) * 1536 + col0 + lc];
      *(short8*)(ks_lds + (((gate << 4) + f) << 9) + (lane << 3)) = v;
    }
  }
  const float* brec = ((role == 0) ? b0v : bsv) + 1536;
  if (tid < 48) bias_l[tid] = brec[(tid >> 4) * 512 + ug0 + (tid & 15)];
  if (tid >= 48 && tid < 96) bias_l[tid] = bsv[((tid - 48) >> 4) * 512 + ug0 + ((tid - 48) & 15)];
  const float a0 = av[0], a1 = av[1], a2 = av[2];
  const float* hinit = (role == 0) ? h00 : (role == 1) ? h01 : h02;

  const int  b0i  = tid >> 4;
  const int  u0   = tid & 15;
  const int  b1i  = (tid + 384) >> 4;
  const bool has1 = (tid < 128);
  const int  uu   = ug0 + u0;
  float hp0 = hinit[uu];
  float hp1 = hp0;

  // role0 xw regs: cur = t, nx = t+1 (prefetch 2 ahead in-loop)
  ushort cz0=0,cr0=0,ch0=0,cz1=0,cr1=0,ch1=0;
  ushort nz0=0,nr0=0,nh0=0,nz1=0,nr1=0,nh1=0;
  if (role == 0){
    size_t r0_ = ((size_t)b0i * 1024) * 1536 + uu;
    cz0 = xw0[r0_]; cr0 = xw0[r0_ + 512]; ch0 = xw0[r0_ + 1024];
    size_t r0b_ = r0_ + 1536;
    nz0 = xw0[r0b_]; nr0 = xw0[r0b_ + 512]; nh0 = xw0[r0b_ + 1024];
    if (has1){
      size_t r1_ = ((size_t)b1i * 1024) * 1536 + uu;
      xz_l0: ;
      cz1 = xw0[r1_]; cr1 = xw0[r1_ + 512]; ch1 = xw0[r1_ + 1024];
      size_t r1b_ = r1_ + 1536;
      nz1 = xw0[r1b_]; nr1 = xw0[r1b_ + 512]; nh1 = xw0[r1b_ + 1024];
    }
  }
  // role2 comb register buffers (8 steps per flush)
  ull cA0 = 0, cB0 = 0, cA1 = 0, cB1 = 0;
  __syncthreads();

  for (int t = 0; t < 1024; ++t){
    const int  slot  = t & (RD - 1);
    const int  pslot = (t - 1) & (RD - 1);
    const uint want  = (uint)(t + 1);
    const uint wantp = (uint)t;            // tag of h[t-1]
    const uint wantb = (uint)(t - 7);      // tag of *[t-8]
    const ull  wrep  = (ull)want | ((ull)want << 32);
    const ull  wrepp = (ull)wantp | ((ull)wantp << 32);

    f32x4 am = {0,0,0,0}, ax = {0,0,0,0};
    float o_s0=0, p_s0=0, x1z0=0, x1r0=0, x1h0=0;
    float o_s1=0, p_s1=0, x1z1=0, x1r1=0, x1h1=0;

    int rtry = 0;
    while (1){
      ull  t64 = 0;
      uint t32 = 0;
      am = (f32x4){0,0,0,0}; ax = (f32x4){0,0,0,0};

      // role2 per-thread scalars (out0, pred0, xw1 at t)
      if (role == 2){
        int rb0 = slot * 16384 + b0i * 512 + uu;
        uint wo = ld_q32(oq + rb0); uint wp = ld_q32(pq + rb0);
        t32 |= (wo ^ want) | (wp ^ want);
        o_s0 = bf2f((ushort)(wo >> 16)); p_s0 = bf2f((ushort)(wp >> 16));
        ull qx = ld_q64(xq + (size_t)((slot * 32 + b0i) * 512 + uu) * 4);
        uint w2 = ld_q32(xq + (size_t)((slot * 32 + b0i) * 512 + uu) * 4 + 2);
        t64 |= (qx ^ wrep); t32 |= (w2 ^ want);
        x1z0 = bf2f((ushort)(((uint)qx) >> 16));
        x1r0 = bf2f((ushort)(((uint)(qx >> 32)) >> 16));
        x1h0 = bf2f((ushort)(w2 >> 16));
        if (has1){
          int rb1 = slot * 16384 + b1i * 512 + uu;
          uint wo1 = ld_q32(oq + rb1); uint wp1 = ld_q32(pq + rb1);
          t32 |= (wo1 ^ want) | (wp1 ^ want);
          o_s1 = bf2f((ushort)(wo1 >> 16)); p_s1 = bf2f((ushort)(wp1 >> 16));
          ull qy = ld_q64(xq + (size_t)((slot * 32 + b1i) * 512 + uu) * 4);
          uint w3 = ld_q32(xq + (size_t)((slot * 32 + b1i) * 512 + uu) * 4 + 2);
          t64 |= (qy ^ wrep); t32 |= (w3 ^ want);
          x1z1 = bf2f((ushort)(((uint)qy) >> 16));
          x1r1 = bf2f((ushort)(((uint)(qy >> 32)) >> 16));
          x1h1 = bf2f((ushort)(w3 >> 16));
        }
      }
      // back-pressure tag checks (wave 0 only, t>=8): readers of slot t-8 done?
      if (t >= RD && wid == 0){
        if (role == 0){
          const uint* q = (lane < 32 ? hq1 : hq2);
          uint w = ld_q32(q + ((t - 8) & (RD - 1)) * 16384 + ((lane & 31) << 4));
          t32 |= (w ^ wantb);
        } else if (role == 1 && lane < 32){
          uint w = ld_q32(hq2 + ((t - 8) & (RD - 1)) * 16384 + (lane << 4));
          t32 |= (w ^ wantb);
        }
      }
      // recurrent A-frags + MFMA (provisional; redo on stale tag)
      if (t == 0){
        #pragma unroll
        for (int f = 0; f < 16; ++f){
          short8 v;
          #pragma unroll
          for (int j = 0; j < 8; ++j)
            v[j] = (short)f2bf(hinit[f * 32 + quad * 8 + j]);
          am = MFMA16(v, bfragR[f], am);
        }
      } else {
        const uint* hr = hq + pslot * 16384 + (mtile * 16 + lc) * 512 + quad * 8;
        #pragma unroll
        for (int f = 0; f < 16; ++f){
          ull q0 = ld_q64(hr + f * 32);
          ull q1 = ld_q64(hr + f * 32 + 2);
          ull q2 = ld_q64(hr + f * 32 + 4);
          ull q3 = ld_q64(hr + f * 32 + 6);
          t64 |= (q0 ^ wrepp) | (q1 ^ wrepp) | (q2 ^ wrepp) | (q3 ^ wrepp);
          union { u32x4 u; short8 s; } pk;
          pk.u = (u32x4){ pk2((uint)(q0 >> 32), (uint)q0),
                          pk2((uint)(q1 >> 32), (uint)q1),
                          pk2((uint)(q2 >> 32), (uint)q2),
                          pk2((uint)(q3 >> 32), (uint)q3) };
          am = MFMA16(pk.s, bfragR[f], am);
        }
      }
      // input-stream A-frags + MFMA (roles 1,2)
      if (role > 0){
        const uint* xr = ((role == 1) ? oq : pq)
                       + slot * 16384 + (mtile * 16 + lc) * 512 + quad * 8;
        #pragma unroll
        for (int f = 0; f < 16; ++f){
          ull q0 = ld_q64(xr + f * 32);
          ull q1 = ld_q64(xr + f * 32 + 2);
          ull q2 = ld_q64(xr + f * 32 + 4);
          ull q3 = ld_q64(xr + f * 32 + 6);
          t64 |= (q0 ^ wrep) | (q1 ^ wrep) | (q2 ^ wrep) | (q3 ^ wrep);
          union { u32x4 u; short8 s; } pk;
          pk.u = (u32x4){ pk2((uint)(q0 >> 32), (uint)q0),
                          pk2((uint)(q1 >> 32), (uint)q1),
                          pk2((uint)(q2 >> 32), (uint)q2),
                          pk2((uint)(q3 >> 32), (uint)q3) };
          short8 bx = *(const short8*)(ks_lds + (((gate << 4) + f) << 9) + (lane << 3));
          ax = MFMA16(pk.s, bx, ax);
        }
      }
      bool ok = ((((uint)(t64 | (t64 >> 32))) | t32) & 0xffffu) == 0u;
      if (__ballot(ok) == ~0ull) break;
      if (++rtry > 400000) break;          // degrade, don't hang
      __builtin_amdgcn_s_sleep(2);
    }

    // role0: issue xw prefetch for t+2 (overlaps MFMA/gates/next retry)
    ushort pz0=0,pr0=0,ph0=0,pz1=0,pr1=0,ph1=0;
    if (role == 0 && t < 1022){
      size_t r0_ = ((size_t)b0i * 1024 + t + 2) * 1536 + uu;
      pz0 = xw0[r0_]; pr0 = xw0[r0_ + 512]; ph0 = xw0[r0_ + 1024];
      if (has1){
        size_t r1_ = ((size_t)b1i * 1024 + t + 2) * 1536 + uu;
        pz1 = xw0[r1_]; pr1 = xw0[r1_ + 512]; ph1 = xw0[r1_ + 1024];
      }
    }
    // role2: flush comb octet [t-8, t-1] (plain HBM stores, amortized)
    if (role == 2 && t >= 8 && (t & 7) == 0){
      #pragma unroll
      for (int j = 0; j < 8; ++j){
        ushort v0 = (ushort)((j < 4 ? (cA0 >> (16 * j)) : (cB0 >> (16 * (j - 4)))) & 0xffff);
        comb[((size_t)b0i * 1024 + (t - 8 + j)) * 512 + uu] = v0;
        if (has1){
          ushort v1 = (ushort)((j < 4 ? (cA1 >> (16 * j)) : (cB1 >> (16 * (j - 4)))) & 0xffff);
          comb[((size_t)b1i * 1024 + (t - 8 + j)) * 512 + uu] = v1;
        }
      }
      cA0 = cB0 = cA1 = cB1 = 0;
    }

    // write m/x partials to LDS
    #pragma unroll
    for (int i = 0; i < 4; ++i)
      m_lds[gate][(mtile << 4) + (quad << 2) + i][lc] = am[i];
    if (role > 0){
      #pragma unroll
      for (int i = 0; i < 4; ++i)
        x_lds[gate][(mtile << 4) + (quad << 2) + i][lc] = ax[i];
    }
    __syncthreads();

    // ---- gate math + tagged ring stores (no drain, no flag) ----
    const uint tv = want & 0xffffu;
    {
      int b = b0i;
      float mz = m_lds[0][b][u0] + bias_l[u0];
      float mr = m_lds[1][b][u0] + bias_l[16 + u0];
      float mh = m_lds[2][b][u0] + bias_l[32 + u0];
      float xz, xr, xh;
      if (role == 0){ xz = bf2f(cz0); xr = bf2f(cr0); xh = bf2f(ch0); }
      else if (role == 1){
        xz = x_lds[0][b][u0] + bias_l[48 + u0];
        xr = x_lds[1][b][u0] + bias_l[64 + u0];
        xh = x_lds[2][b][u0] + bias_l[80 + u0];
      } else {
        xz = x1z0 + a0 * x_lds[0][b][u0] + bias_l[48 + u0];
        xr = x1r0 + a0 * x_lds[1][b][u0] + bias_l[64 + u0];
        xh = x1h0 + a0 * x_lds[2][b][u0] + bias_l[80 + u0];
      }
      float z  = 1.f / (1.f + __expf(-(xz + mz)));
      float r  = 1.f / (1.f + __expf(-(xr + mr)));
      float axv = xh + r * mh;
      float hh = 1.f - 2.f / (1.f + __expf(2.f * axv));
      float hn = z * hp0 + (1.f - z) * hh;
      float hcv = hn + 0.1f * (hp0 - hn);
      hp0 = hcv;
      int rb = slot * 16384 + b * 512 + uu;
      st_q32(hq + rb, ((uint)f2bf(hcv) << 16) | tv);
      if (role == 0) st_q32(oq + rb, ((uint)f2bf(hn) << 16) | tv);
      else if (role == 1){
        st_q32(pq + rb, ((uint)f2bf(hn) << 16) | tv);
        uint w0 = ((uint)f2bf(x_lds[0][b][u0]) << 16) | tv;
        uint w1 = ((uint)f2bf(x_lds[1][b][u0]) << 16) | tv;
        uint w2 = ((uint)f2bf(x_lds[2][b][u0]) << 16) | tv;
        uint* xb = xq + (size_t)((slot * 32 + b) * 512 + uu) * 4;
        st_q64(xb, (ull)w0 | ((ull)w1 << 32));
        st_q32(xb + 2, w2);
      } else {
        ull v = (ull)f2bf(o_s0 + a1 * p_s0 + a2 * hn);
        int sh = (t & 3) * 16;
        if (t & 4) cB0 |= v << sh; else cA0 |= v << sh;
      }
    }
    if (has1){
      int b = b1i;
      float mz = m_lds[0][b][u0] + bias_l[u0];
      float mr = m_lds[1][b][u0] + bias_l[16 + u0];
      float mh = m_lds[2][b][u0] + bias_l[32 + u0];
      float xz, xr, xh;
      if (role == 0){ xz = bf2f(cz1); xr = bf2f(cr1); xh = bf2f(ch1); }
      else if (role == 1){
        xz = x_lds[0][b][u0] + bias_l[48 + u0];
        xr = x_lds[1][b][u0] + bias_l[64 + u0];
        xh = x_lds[2][b][u0] + bias_l[80 + u0];
      } else {
        xz = x1z1 + a0 * x_lds[0][b][u0] + bias_l[48 + u0];
        xr = x1r1 + a0 * x_lds[1][b][u0] + bias_l[64 + u0];
        xh = x1h1 + a0 * x_lds[2][b][u0] + bias_l[80 + u0];
      }
      float z  = 1.f / (1.f + __expf(-(xz + mz)));
      float r  = 1.f / (1.f + __expf(-(xr + mr)));
      float axv = xh + r * mh;
      float hh = 1.f - 2.f / (1.f + __expf(2.f * axv));
      float hn = z * hp1 + (1.f - z) * hh;
      float hcv = hn + 0.1f * (hp1 - hn);
      hp1 = hcv;
      int rb = slot * 16384 + b * 512 + uu;
      st_q32(hq + rb, ((uint)f2bf(hcv) << 16) | tv);
      if (role == 0) st_q32(oq + rb, ((uint)f2bf(hn) << 16) | tv);
      else if (role == 1){
        st_q32(pq + rb, ((uint)f2bf(hn) << 16) | tv);
        uint w0 = ((uint)f2bf(x_lds[0][b][u0]) << 16) | tv;
        uint w1 = ((uint)f2bf(x_lds[1][b][u0]) << 16) | tv;
        uint w2 = ((uint)f2bf(x_lds[2][b][u0]) << 16) | tv;
        uint* xb = xq + (size_t)((slot * 32 + b) * 512 + uu) * 4;
        st_q64(xb, (ull)w0 | ((ull)w1 << 32));
        st_q32(xb + 2, w2);
      } else {
        ull v = (ull)f2bf(o_s1 + a1 * p_s1 + a2 * hn);
        int sh = (t & 3) * 16;
        if (t & 4) cB1 |= v << sh; else cA1 |= v << sh;
      }
    }
    __syncthreads();   // WG-internal step boundary (no vmem drain attached)

    if (role == 0){
      cz0 = nz0; cr0 = nr0; ch0 = nh0; cz1 = nz1; cr1 = nr1; ch1 = nh1;
      nz0 = pz0; nr0 = pr0; nh0 = ph0; nz1 = pz1; nr1 = pr1; nh1 = ph1;
    }
  }
  // role2: final comb octet [1016,1023]
  if (role == 2){
    #pragma unroll
    for (int j = 0; j < 8; ++j){
      ushort v0 = (ushort)((j < 4 ? (cA0 >> (16 * j)) : (cB0 >> (16 * (j - 4)))) & 0xffff);
      comb[((size_t)b0i * 1024 + (1016 + j)) * 512 + uu] = v0;
      if (has1){
        ushort v1 = (ushort)((j < 4 ? (cA1 >> (16 * j)) : (cB1 >> (16 * (j - 4)))) & 0xffff);
        comb[((size_t)b1i * 1024 + (1016 + j)) * 512 + uu] = v1;
      }
    }
  }
}

// ---------------------------------------------------------------------------
extern "C" void kernel_launch(void* const* d_in, const int* in_sizes, int n_in,
                              void* d_out, int out_size, void* d_ws, size_t ws_size,
                              hipStream_t stream)
{
  const float* x   = (const float*)d_in[0];
  const float* k0  = (const float*)d_in[1];
  const float* r0  = (const float*)d_in[2];
  const float* b0  = (const float*)d_in[3];
  const float* ks  = (const float*)d_in[4];
  const float* rs  = (const float*)d_in[5];
  const float* bs  = (const float*)d_in[6];
  const float* h00 = (const float*)d_in[7];
  const float* h01 = (const float*)d_in[8];
  const float* h02 = (const float*)d_in[9];
  const float* a   = (const float*)d_in[10];
  const float* wd  = (const float*)d_in[11];
  const float* bd  = (const float*)d_in[12];
  float* outp = (float*)d_out;

  // ws layout (bytes):
  //   [0,        100663296)  XW0   [32768,1536] bf16
  //   [100663296,134217728)  comb  [32768,512] bf16 (first 16.8MB aliases x_bf)
  //   [134217728,138936320)  tagged rings (4.5 MB u32)
  //   [138936320,...]        bf16 weights k0b,r0b,ksb,rsb,wdb
  char* ws = (char*)d_ws;
  ushort* XW    = (ushort*)(ws);
  ushort* combp = (ushort*)(ws + 100663296u);
  ushort* xbf   = combp;                      // alias: dead before rec3_k runs
  uint*   ringsq= (uint*)  (ws + 134217728u);
  ushort* k0b   = (ushort*)(ws + 138936320u);
  ushort* r0b   = (ushort*)(ws + 139722752u);
  ushort* ksb   = (ushort*)(ws + 141295616u);
  ushort* rsb   = (ushort*)(ws + 142868480u);
  ushort* wdb   = (ushort*)(ws + 144441344u);

  // poison rings: tag 0xAAAA never matches a valid epoch (<=1024)
  hipMemsetAsync(ringsq, 0xAA, 1179648u * sizeof(uint), stream);

  dim3 blk(256);
  cvt_k<<<dim3(8192), blk, 0, stream>>>(x,  xbf, 8388608);
  cvt_k<<<dim3(384),  blk, 0, stream>>>(k0, k0b, 393216);
  cvt_k<<<dim3(768),  blk, 0, stream>>>(r0, r0b, 786432);
  cvt_k<<<dim3(768),  blk, 0, stream>>>(ks, ksb, 786432);
  cvt_k<<<dim3(768),  blk, 0, stream>>>(rs, rsb, 786432);
  cvt_k<<<dim3(128),  blk, 0, stream>>>(wd, wdb, 131072);

  // Layer-0 input projection (bulk GEMM)
  gemm_bias_k<0><<<dim3(512 * 24), blk, 0, stream>>>(xbf, k0b, b0, XW, 32768, 1536, 256);
  // Fused pipelined 3-layer recurrence (tagged-epoch protocol)
  rec3_k<<<dim3(NWG), dim3(384), 0, stream>>>(XW, r0b, ksb, rsb, b0, bs,
                                              h00, h01, h02, a, combp, ringsq);
  // Final projection: comb @ wd + bd -> fp32 d_out
  gemm_bias_k<1><<<dim3(512 * 4), blk, 0, stream>>>(combp, wdb, bd, outp, 32768, 256, 512);
}